// Round 9
// baseline (1110.701 us; speedup 1.0000x reference)
//
#include <hip/hip_runtime.h>

#define D 64
#define WQ_BITS 15
#define WQ_MAX 32767.0f
#define MAXBINS 512        // bins of 256 nodes; N <= 131072 guarded
#define CAPB 5120          // entries per bin; mean 4092 at N=100k,E=1.6M (+16 sigma)
#define OVCAP 131072       // overflow list capacity (never fires in practice)

typedef int   int4v   __attribute__((ext_vector_type(4)));
typedef float float4v __attribute__((ext_vector_type(4)));

__device__ __forceinline__ ushort f2bf(float x) {
    unsigned u = __float_as_uint(x);
    unsigned r = (u + 0x7fff + ((u >> 16) & 1)) >> 16;  // round-to-nearest-even
    return (ushort)r;
}
__device__ __forceinline__ float bf2f(ushort u) {
    return __uint_as_float(((unsigned)u) << 16);
}

// ---------------------------------------------------------------------------
// Phase 1: LDS-staged binning. One pass over edges (NT reads). Entries are
// staged 8-per-bin in LDS and flushed as full 64 B lines -> line-granular
// writes (round-4/8 lesson: per-edge random 4 B stores = 8x write amp, 68 MB).
// entry = { x: src<<15 | wq15, y: dst&255 }
__global__ __launch_bounds__(1024) void bin_scatter_kernel(
    const int* __restrict__ src, const int* __restrict__ dst,
    const float* __restrict__ w, int* __restrict__ binCursor,
    uint2* __restrict__ binned, uint2* __restrict__ ovList,
    int* __restrict__ ovCur, int E)
{
    __shared__ uint2 stage[MAXBINS * 8];   // 32 KB
    __shared__ int   cnt[MAXBINS];         // 2 KB
    int tid = threadIdx.x;
    if (tid < MAXBINS) cnt[tid] = 0;
    __syncthreads();

    int stride = gridDim.x * 1024;
    int rounds = (E + stride - 1) / stride;   // uniform across blocks
    int e = blockIdx.x * 1024 + tid;

    for (int r = 0; r < rounds; ++r, e += stride) {
        if (e < E) {
            int d    = __builtin_nontemporal_load(&dst[e]);
            int s    = __builtin_nontemporal_load(&src[e]);
            float wr = __builtin_nontemporal_load(&w[e]);
            float wv = fminf(fmaxf(wr, 0.f), 1.f);
            unsigned wq = (unsigned)(wv * WQ_MAX + 0.5f);
            uint2 entry = make_uint2(((unsigned)s << WQ_BITS) | wq,
                                     (unsigned)(d & 255));
            int bin = d >> 8;
            int pos = atomicAdd(&cnt[bin], 1);
            if (pos < 8) {
                stage[bin * 8 + pos] = entry;
            } else {  // rare same-round overflow of the stage: direct global
                int gp = atomicAdd(&binCursor[bin], 1);
                if (gp < CAPB) binned[(size_t)bin * CAPB + gp] = entry;
                else {
                    int op = atomicAdd(ovCur, 1);
                    if (op < OVCAP) ovList[op] = make_uint2(entry.x, (unsigned)d);
                }
            }
        }
        __syncthreads();
        if (tid < MAXBINS) {
            int c = cnt[tid];
            if (c >= 8) {  // stage full: flush one 64 B line
                int base = atomicAdd(&binCursor[tid], 8);
                #pragma unroll
                for (int k = 0; k < 8; ++k) {
                    uint2 v = stage[tid * 8 + k];
                    int gp = base + k;
                    if (gp < CAPB) binned[(size_t)tid * CAPB + gp] = v;
                    else {
                        int op = atomicAdd(ovCur, 1);
                        if (op < OVCAP)
                            ovList[op] = make_uint2(v.x, (unsigned)(tid * 256 + (int)(v.y & 255)));
                    }
                }
                cnt[tid] = 0;
            }
        }
        __syncthreads();
    }
    // drain residues (<8 entries per bin per block)
    if (tid < MAXBINS) {
        int c = min(cnt[tid], 8);
        if (c > 0) {
            int base = atomicAdd(&binCursor[tid], c);
            for (int k = 0; k < c; ++k) {
                uint2 v = stage[tid * 8 + k];
                int gp = base + k;
                if (gp < CAPB) binned[(size_t)tid * CAPB + gp] = v;
                else {
                    int op = atomicAdd(ovCur, 1);
                    if (op < OVCAP)
                        ovList[op] = make_uint2(v.x, (unsigned)(tid * 256 + (int)(v.y & 255)));
                }
            }
        }
    }
}

// ---------------------------------------------------------------------------
// Fused GEMM: out[n][j] = b[j] + sum_k h[n][k]*W[j][k]        (fp32)
//             g[n][j]   =        sum_k h[n][k]*W[j][64+k]     (bf16 store)
// 64 nodes/block, 4 nodes x 4 cols per thread, LDS-only inner reads,
// unroll 4 (round-2 lesson: full unroll -> 256 VGPR spill).
__global__ __launch_bounds__(256) void gemm_fused_kernel(
    const float* __restrict__ h, const float* __restrict__ W,
    const float* __restrict__ b, float* __restrict__ out,
    ushort* __restrict__ g, int N)
{
    __shared__ float Wt[128 * 64];  // Wt[k*64+j] = W[j*128+k]
    __shared__ float Xt[64 * 64];   // Xt[k*64+n] = h[(n0+n)*64+k]
    int tid = threadIdx.x;

    for (int idx = tid; idx < 128 * 64; idx += 256) {
        int j = idx & 63;
        int k = idx >> 6;
        Wt[k * 64 + j] = W[j * 128 + k];
    }

    int n0blk = blockIdx.x * 64;
    {
        int n = tid & 63;
        int krow = tid >> 6;  // 0..3
        int nn = min(n0blk + n, N - 1);
        #pragma unroll
        for (int c = 0; c < 4; ++c) {
            int k0 = (krow + c * 4) * 4;
            float4 v = *(const float4*)&h[(size_t)nn * D + k0];
            Xt[(k0 + 0) * 64 + n] = v.x;
            Xt[(k0 + 1) * 64 + n] = v.y;
            Xt[(k0 + 2) * 64 + n] = v.z;
            Xt[(k0 + 3) * 64 + n] = v.w;
        }
    }
    __syncthreads();

    int j0 = (tid & 15) * 4;
    int nb = (tid >> 4) * 4;

    float4 bv = *(const float4*)&b[j0];
    float accS[4][4], accG[4][4];
    #pragma unroll
    for (int i = 0; i < 4; ++i) {
        accS[i][0] = bv.x; accS[i][1] = bv.y; accS[i][2] = bv.z; accS[i][3] = bv.w;
        accG[i][0] = 0.f;  accG[i][1] = 0.f;  accG[i][2] = 0.f;  accG[i][3] = 0.f;
    }

    #pragma unroll 4
    for (int k = 0; k < 64; ++k) {
        float4 xv = *(const float4*)&Xt[k * 64 + nb];
        float4 w1 = *(const float4*)&Wt[k * 64 + j0];
        float4 w2 = *(const float4*)&Wt[(k + 64) * 64 + j0];
        #pragma unroll
        for (int i = 0; i < 4; ++i) {
            float x = (&xv.x)[i];
            accS[i][0] += x * w1.x; accS[i][1] += x * w1.y;
            accS[i][2] += x * w1.z; accS[i][3] += x * w1.w;
            accG[i][0] += x * w2.x; accG[i][1] += x * w2.y;
            accG[i][2] += x * w2.z; accG[i][3] += x * w2.w;
        }
    }

    #pragma unroll
    for (int i = 0; i < 4; ++i) {
        int n = n0blk + nb + i;
        if (n < N) {
            *(float4*)&out[(size_t)n * D + j0] =
                make_float4(accS[i][0], accS[i][1], accS[i][2], accS[i][3]);
            ushort4 gv;
            gv.x = f2bf(accG[i][0]); gv.y = f2bf(accG[i][1]);
            gv.z = f2bf(accG[i][2]); gv.w = f2bf(accG[i][3]);
            *(ushort4*)&g[(size_t)n * D + j0] = gv;
        }
    }
}

// ---------------------------------------------------------------------------
// Phase 2: per-half-bin aggregation in LDS. blockIdx = bin*2 + half; each
// block owns 128 node rows (32 KB fp32 acc). Entries streamed coalesced,
// g rows gathered with MLP-8, accumulated via native LDS float atomics,
// then one coalesced out += acc pass.
__global__ __launch_bounds__(256) void bin_agg_kernel(
    const ushort* __restrict__ g, const uint2* __restrict__ binned,
    const int* __restrict__ binCursor, float* __restrict__ out, int N)
{
    __shared__ float acc[128 * 64];  // 32 KB
    int bin  = blockIdx.x >> 1;
    int half = blockIdx.x & 1;
    int tid  = threadIdx.x;
    int wave = tid >> 6, lane = tid & 63;

    for (int i = tid; i < 128 * 64; i += 256) acc[i] = 0.f;
    __syncthreads();

    int cnt = min(binCursor[bin], CAPB);
    const uint2* eb = binned + (size_t)bin * CAPB;
    const float wscale = 1.0f / WQ_MAX;

    for (int base = wave * 64; base < cnt; base += 4 * 64) {
        int m = min(64, cnt - base);
        uint2 my = (base + lane < cnt) ? eb[base + lane] : make_uint2(0u, 0u);
        int j = 0;
        for (; j + 8 <= m; j += 8) {
            unsigned cx[8], cy[8];
            #pragma unroll
            for (int u = 0; u < 8; ++u) {
                cx[u] = __shfl(my.x, j + u);
                cy[u] = __shfl(my.y, j + u);
            }
            float v[8];
            #pragma unroll
            for (int u = 0; u < 8; ++u)
                if ((cy[u] >> 7) == (unsigned)half)
                    v[u] = bf2f(g[(size_t)(cx[u] >> WQ_BITS) * D + lane]);
            #pragma unroll
            for (int u = 0; u < 8; ++u)
                if ((cy[u] >> 7) == (unsigned)half)
                    atomicAdd(&acc[(cy[u] & 127) * 64 + lane],
                              (float)(cx[u] & 0x7fffu) * wscale * v[u]);
        }
        for (; j < m; ++j) {
            unsigned cx = __shfl(my.x, j);
            unsigned cy = __shfl(my.y, j);
            if ((cy >> 7) == (unsigned)half) {
                float v = bf2f(g[(size_t)(cx >> WQ_BITS) * D + lane]);
                atomicAdd(&acc[(cy & 127) * 64 + lane],
                          (float)(cx & 0x7fffu) * wscale * v);
            }
        }
    }
    __syncthreads();

    for (int r = wave; r < 128; r += 4) {
        int n = bin * 256 + half * 128 + r;
        if (n < N)
            out[(size_t)n * D + lane] += acc[r * 64 + lane];
    }
}

// ---------------------------------------------------------------------------
// Overflow cleanup: one wave per overflow entry (empty in practice).
__global__ __launch_bounds__(256) void ov_kernel(
    const uint2* __restrict__ ovList, const int* __restrict__ ovCur,
    const ushort* __restrict__ g, float* __restrict__ out)
{
    int cnt = min(*ovCur, OVCAP);
    int lane = threadIdx.x & 63;
    int wv = blockIdx.x * 4 + (threadIdx.x >> 6);
    for (int i = wv; i < cnt; i += gridDim.x * 4) {
        uint2 en = ovList[i];
        int dn = (int)en.y;
        int sn = (int)(en.x >> WQ_BITS);
        float wt = (float)(en.x & 0x7fffu) * (1.0f / WQ_MAX);
        atomicAdd(&out[(size_t)dn * D + lane], wt * bf2f(g[(size_t)sn * D + lane]));
    }
}

// ---------------------------------------------------------------------------
// Fallback path (small ws / big N): round-1 kernels, known-good.
__global__ __launch_bounds__(256) void edge_scatter_kernel(
    const float* __restrict__ h, const float* __restrict__ w,
    const int* __restrict__ src, const int* __restrict__ dst,
    float* __restrict__ agg, int E)
{
    int e = blockIdx.x * 4 + (threadIdx.x >> 6);
    int lane = threadIdx.x & 63;
    if (e >= E) return;
    float val = w[e] * h[(size_t)src[e] * D + lane];
    atomicAdd(&agg[(size_t)dst[e] * D + lane], val);
}

__global__ __launch_bounds__(256) void out_linear_kernel(
    const float* __restrict__ h, const float* __restrict__ agg,
    const float* __restrict__ W, const float* __restrict__ b,
    float* __restrict__ out, int N)
{
    __shared__ float Wt[128 * 64];
    int lane = threadIdx.x & 63;
    int waveInBlock = threadIdx.x >> 6;
    int wavesPerBlock = blockDim.x >> 6;
    for (int idx = threadIdx.x; idx < 128 * 64; idx += blockDim.x) {
        int j = idx & 63;
        int k = idx >> 6;
        Wt[k * 64 + j] = W[j * 128 + k];
    }
    __syncthreads();
    float bj = b[lane];
    int wavesPerGrid = gridDim.x * wavesPerBlock;
    for (int n = blockIdx.x * wavesPerBlock + waveInBlock; n < N; n += wavesPerGrid) {
        float hreg = h[(size_t)n * D + lane];
        float areg = agg[(size_t)n * D + lane];
        float acc = bj;
        #pragma unroll
        for (int k = 0; k < 64; ++k) {
            float hk = __shfl(hreg, k, 64);
            float ak = __shfl(areg, k, 64);
            acc += hk * Wt[k * 64 + lane];
            acc += ak * Wt[(k + 64) * 64 + lane];
        }
        out[(size_t)n * D + lane] = acc;
    }
}

// ---------------------------------------------------------------------------
extern "C" void kernel_launch(void* const* d_in, const int* in_sizes, int n_in,
                              void* d_out, int out_size, void* d_ws, size_t ws_size,
                              hipStream_t stream) {
    const float* h   = (const float*)d_in[0];
    const float* w   = (const float*)d_in[1];
    const int*   src = (const int*)d_in[2];
    const int*   dst = (const int*)d_in[3];
    const float* W   = (const float*)d_in[4];
    const float* b   = (const float*)d_in[5];
    float* out = (float*)d_out;

    int N = in_sizes[0] / D;
    int E = in_sizes[1];

    auto align256 = [](size_t x) { return (x + 255) & ~(size_t)255; };
    size_t curB    = align256(MAXBINS * 4 + 256);          // binCursor + ovCur
    size_t binnedB = align256((size_t)MAXBINS * CAPB * 8); // 21 MB
    size_t ovB     = align256((size_t)OVCAP * 8);          // 1 MB
    size_t gB      = align256((size_t)N * D * 2);          // 12.8 MB
    size_t need = curB + binnedB + ovB + gB;

    if (ws_size >= need && N <= (1 << 17)) {
        char* p = (char*)d_ws;
        int*   binCursor = (int*)p;               // [0, MAXBINS)
        int*   ovCur     = (int*)(p + MAXBINS*4); // right after
        p += curB;
        uint2* binned = (uint2*)p;  p += binnedB;
        uint2* ovList = (uint2*)p;  p += ovB;
        ushort* g     = (ushort*)p;

        hipMemsetAsync(binCursor, 0, curB, stream);

        int nbins = (N + 255) >> 8;
        bin_scatter_kernel<<<160, 1024, 0, stream>>>(src, dst, w, binCursor,
                                                     binned, ovList, ovCur, E);
        gemm_fused_kernel<<<(N + 63) / 64, 256, 0, stream>>>(h, W, b, out, g, N);
        bin_agg_kernel<<<nbins * 2, 256, 0, stream>>>(g, binned, binCursor, out, N);
        ov_kernel<<<64, 256, 0, stream>>>(ovList, ovCur, g, out);
    } else {
        float* agg = out;
        hipMemsetAsync(agg, 0, (size_t)N * D * 4, stream);
        edge_scatter_kernel<<<(E + 3) / 4, 256, 0, stream>>>(h, w, src, dst, agg, E);
        out_linear_kernel<<<2048, 256, 0, stream>>>(h, agg, W, b, out, N);
    }
}

// Round 10
// 250.877 us; speedup vs baseline: 4.4273x; 4.4273x over previous
//
#include <hip/hip_runtime.h>

#define D 64
#define CAP 64          // per-node bucket capacity (avg degree 16; P(>64) ~ 1e-20)
#define WQ_BITS 15
#define WQ_MAX 32767.0f
#define NSHARDS 8       // = XCD count; blockIdx%8 -> XCD round-robin heuristic

// native clang vectors: __builtin_nontemporal_load rejects HIP_vector_type
// classes (round-6 compile failure) but accepts ext_vector_type.
typedef int   int4v   __attribute__((ext_vector_type(4)));
typedef float float4v __attribute__((ext_vector_type(4)));

__device__ __forceinline__ ushort f2bf(float x) {
    unsigned u = __float_as_uint(x);
    unsigned r = (u + 0x7fff + ((u >> 16) & 1)) >> 16;  // round-to-nearest-even
    return (ushort)r;
}
__device__ __forceinline__ float bf2f(ushort u) {
    return __uint_as_float(((unsigned)u) << 16);
}

// ---------------------------------------------------------------------------
// XCD-sharded scatter (round-8 known-good). shard = blockIdx%8 -> XCD.
// Round-9 lesson: LDS-staged binning + syncthreads-per-round flushes are
// SLOWER (237 us) than this direct atomic-cursor scatter (86 us); LDS fp32
// atomics in the aggregator cost ~1 per lane-edge = 833 us. Reverted.
// 4096 blocks: round 7->8 showed occupancy is the limiter (512->2048 gave
// 112->86 us).
__global__ __launch_bounds__(256) void scatter_shard_kernel(
    const int* __restrict__ src, const int* __restrict__ dst,
    const float* __restrict__ w, int* __restrict__ cursor,
    unsigned* __restrict__ ovBits, unsigned* __restrict__ pairs,
    int E, int N)
{
    int shard   = blockIdx.x & (NSHARDS - 1);
    int slice   = blockIdx.x >> 3;
    int nSlices = gridDim.x >> 3;
    int n8 = (N + NSHARDS - 1) / NSHARDS;
    int lo = shard * n8;
    int hi = min(N, lo + n8);

    int e4 = E >> 2;  // full int4 groups
    for (int gi = slice * 256 + threadIdx.x; gi < e4; gi += nSlices * 256) {
        int e0 = gi * 4;
        int4v d4 = __builtin_nontemporal_load((const int4v*)&dst[e0]);
        #pragma unroll
        for (int i = 0; i < 4; ++i) {
            int d = d4[i];
            if (d >= lo && d < hi) {
                int e = e0 + i;
                int sv = __builtin_nontemporal_load(&src[e]);
                float wvr = __builtin_nontemporal_load(&w[e]);
                int pos = atomicAdd(&cursor[d], 1);
                if (pos < CAP) {
                    float wv = fminf(fmaxf(wvr, 0.f), 1.f);
                    unsigned wq = (unsigned)(wv * WQ_MAX + 0.5f);
                    pairs[(size_t)d * CAP + pos] =
                        ((unsigned)sv << WQ_BITS) | wq;
                } else {
                    atomicOr(&ovBits[e >> 5], 1u << (e & 31));
                }
            }
        }
    }
    // tail (E % 4 edges), filtered by the same shard predicate
    for (int e = e4 * 4 + slice * 256 + threadIdx.x; e < E; e += nSlices * 256) {
        int d = dst[e];
        if (d >= lo && d < hi) {
            int pos = atomicAdd(&cursor[d], 1);
            if (pos < CAP) {
                float wv = fminf(fmaxf(w[e], 0.f), 1.f);
                unsigned wq = (unsigned)(wv * WQ_MAX + 0.5f);
                pairs[(size_t)d * CAP + pos] =
                    ((unsigned)src[e] << WQ_BITS) | wq;
            } else {
                atomicOr(&ovBits[e >> 5], 1u << (e & 31));
            }
        }
    }
}

// ---------------------------------------------------------------------------
// Fused GEMM: out[n][j] = b[j] + sum_k h[n][k]*W[j][k]        (fp32)
//             g[n][j]   =        sum_k h[n][k]*W[j][64+k]     (bf16 store)
// 64 nodes/block, 4 nodes x 4 cols per thread, LDS-only inner reads,
// unroll 4 (round-2 lesson: full unroll -> 256 VGPR spill).
__global__ __launch_bounds__(256) void gemm_fused_kernel(
    const float* __restrict__ h, const float* __restrict__ W,
    const float* __restrict__ b, float* __restrict__ out,
    ushort* __restrict__ g, int N)
{
    __shared__ float Wt[128 * 64];  // Wt[k*64+j] = W[j*128+k]
    __shared__ float Xt[64 * 64];   // Xt[k*64+n] = h[(n0+n)*64+k]
    int tid = threadIdx.x;

    for (int idx = tid; idx < 128 * 64; idx += 256) {
        int j = idx & 63;
        int k = idx >> 6;
        Wt[k * 64 + j] = W[j * 128 + k];
    }

    int n0blk = blockIdx.x * 64;
    {
        int n = tid & 63;
        int krow = tid >> 6;  // 0..3
        int nn = min(n0blk + n, N - 1);
        #pragma unroll
        for (int c = 0; c < 4; ++c) {
            int k0 = (krow + c * 4) * 4;
            float4 v = *(const float4*)&h[(size_t)nn * D + k0];
            Xt[(k0 + 0) * 64 + n] = v.x;
            Xt[(k0 + 1) * 64 + n] = v.y;
            Xt[(k0 + 2) * 64 + n] = v.z;
            Xt[(k0 + 3) * 64 + n] = v.w;
        }
    }
    __syncthreads();

    int j0 = (tid & 15) * 4;
    int nb = (tid >> 4) * 4;

    float4 bv = *(const float4*)&b[j0];
    float accS[4][4], accG[4][4];
    #pragma unroll
    for (int i = 0; i < 4; ++i) {
        accS[i][0] = bv.x; accS[i][1] = bv.y; accS[i][2] = bv.z; accS[i][3] = bv.w;
        accG[i][0] = 0.f;  accG[i][1] = 0.f;  accG[i][2] = 0.f;  accG[i][3] = 0.f;
    }

    #pragma unroll 4
    for (int k = 0; k < 64; ++k) {
        float4 xv = *(const float4*)&Xt[k * 64 + nb];
        float4 w1 = *(const float4*)&Wt[k * 64 + j0];
        float4 w2 = *(const float4*)&Wt[(k + 64) * 64 + j0];
        #pragma unroll
        for (int i = 0; i < 4; ++i) {
            float x = (&xv.x)[i];
            accS[i][0] += x * w1.x; accS[i][1] += x * w1.y;
            accS[i][2] += x * w1.z; accS[i][3] += x * w1.w;
            accG[i][0] += x * w2.x; accG[i][1] += x * w2.y;
            accG[i][2] += x * w2.z; accG[i][3] += x * w2.w;
        }
    }

    #pragma unroll
    for (int i = 0; i < 4; ++i) {
        int n = n0blk + nb + i;
        if (n < N) {
            *(float4*)&out[(size_t)n * D + j0] =
                make_float4(accS[i][0], accS[i][1], accS[i][2], accS[i][3]);
            ushort4 gv;
            gv.x = f2bf(accG[i][0]); gv.y = f2bf(accG[i][1]);
            gv.z = f2bf(accG[i][2]); gv.w = f2bf(accG[i][3]);
            *(ushort4*)&g[(size_t)n * D + j0] = gv;
        }
    }
}

// ---------------------------------------------------------------------------
// Final: out[n] += sum over bucket(n) of w_e * g_bf16[src_e].
// One wave per node. All <=64 pair codes arrive in ONE coalesced 256 B load,
// broadcast via shfl. MLP-16 first tier: avg degree is 16, so most waves
// complete all gathers in ONE latency round (round-8 had MLP-8 = 2 rounds).
__global__ __launch_bounds__(256) void final_agg_kernel(
    const ushort* __restrict__ g, const unsigned* __restrict__ pairs,
    const int* __restrict__ cursor, float* __restrict__ out, int N)
{
    int wave = threadIdx.x >> 6;
    int lane = threadIdx.x & 63;
    int n = blockIdx.x * 4 + wave;
    if (n >= N) return;
    int cnt = min(cursor[n], CAP);
    unsigned mycode = pairs[(size_t)n * CAP + lane];  // coalesced 256 B
    float acc = out[(size_t)n * D + lane];

    const float wscale = 1.0f / WQ_MAX;
    int j = 0;
    for (; j + 16 <= cnt; j += 16) {
        unsigned c[16];
        float v[16];
        #pragma unroll
        for (int u = 0; u < 16; ++u) c[u] = __shfl(mycode, j + u);
        #pragma unroll
        for (int u = 0; u < 16; ++u)
            v[u] = bf2f(g[(size_t)(c[u] >> WQ_BITS) * D + lane]);
        #pragma unroll
        for (int u = 0; u < 16; ++u)
            acc += (float)(c[u] & 0x7fffu) * wscale * v[u];
    }
    for (; j + 8 <= cnt; j += 8) {
        unsigned c[8];
        float v[8];
        #pragma unroll
        for (int u = 0; u < 8; ++u) c[u] = __shfl(mycode, j + u);
        #pragma unroll
        for (int u = 0; u < 8; ++u)
            v[u] = bf2f(g[(size_t)(c[u] >> WQ_BITS) * D + lane]);
        #pragma unroll
        for (int u = 0; u < 8; ++u)
            acc += (float)(c[u] & 0x7fffu) * wscale * v[u];
    }
    for (; j + 4 <= cnt; j += 4) {
        unsigned c[4];
        float v[4];
        #pragma unroll
        for (int u = 0; u < 4; ++u) c[u] = __shfl(mycode, j + u);
        #pragma unroll
        for (int u = 0; u < 4; ++u)
            v[u] = bf2f(g[(size_t)(c[u] >> WQ_BITS) * D + lane]);
        #pragma unroll
        for (int u = 0; u < 4; ++u)
            acc += (float)(c[u] & 0x7fffu) * wscale * v[u];
    }
    for (; j < cnt; ++j) {
        unsigned c = __shfl(mycode, j);
        acc += (float)(c & 0x7fffu) * wscale *
               bf2f(g[(size_t)(c >> WQ_BITS) * D + lane]);
    }
    out[(size_t)n * D + lane] = acc;
}

// ---------------------------------------------------------------------------
// Overflow cleanup (runs after final_agg; empty for sane degree distributions).
__global__ __launch_bounds__(256) void overflow_kernel(
    const unsigned* __restrict__ ovBits, const int* __restrict__ src,
    const int* __restrict__ dst, const float* __restrict__ w,
    const ushort* __restrict__ g, float* __restrict__ out, int numWords)
{
    int idx = blockIdx.x * 256 + threadIdx.x;
    for (int wi = idx; wi < numWords; wi += gridDim.x * 256) {
        unsigned bits = ovBits[wi];
        while (bits) {
            int bit = __ffs(bits) - 1;
            bits &= bits - 1;
            int e = wi * 32 + bit;
            int s = src[e], d = dst[e];
            float wv = w[e];
            for (int f = 0; f < D; ++f)
                atomicAdd(&out[(size_t)d * D + f], wv * bf2f(g[(size_t)s * D + f]));
        }
    }
}

// ---------------------------------------------------------------------------
// Fallback path (small ws / big N): round-1 kernels, known-good.
__global__ __launch_bounds__(256) void edge_scatter_kernel(
    const float* __restrict__ h, const float* __restrict__ w,
    const int* __restrict__ src, const int* __restrict__ dst,
    float* __restrict__ agg, int E)
{
    int e = blockIdx.x * 4 + (threadIdx.x >> 6);
    int lane = threadIdx.x & 63;
    if (e >= E) return;
    float val = w[e] * h[(size_t)src[e] * D + lane];
    atomicAdd(&agg[(size_t)dst[e] * D + lane], val);
}

__global__ __launch_bounds__(256) void out_linear_kernel(
    const float* __restrict__ h, const float* __restrict__ agg,
    const float* __restrict__ W, const float* __restrict__ b,
    float* __restrict__ out, int N)
{
    __shared__ float Wt[128 * 64];
    int lane = threadIdx.x & 63;
    int waveInBlock = threadIdx.x >> 6;
    int wavesPerBlock = blockDim.x >> 6;
    for (int idx = threadIdx.x; idx < 128 * 64; idx += blockDim.x) {
        int j = idx & 63;
        int k = idx >> 6;
        Wt[k * 64 + j] = W[j * 128 + k];
    }
    __syncthreads();
    float bj = b[lane];
    int wavesPerGrid = gridDim.x * wavesPerBlock;
    for (int n = blockIdx.x * wavesPerBlock + waveInBlock; n < N; n += wavesPerGrid) {
        float hreg = h[(size_t)n * D + lane];
        float areg = agg[(size_t)n * D + lane];
        float acc = bj;
        #pragma unroll
        for (int k = 0; k < 64; ++k) {
            float hk = __shfl(hreg, k, 64);
            float ak = __shfl(areg, k, 64);
            acc += hk * Wt[k * 64 + lane];
            acc += ak * Wt[(k + 64) * 64 + lane];
        }
        out[(size_t)n * D + lane] = acc;
    }
}

// ---------------------------------------------------------------------------
extern "C" void kernel_launch(void* const* d_in, const int* in_sizes, int n_in,
                              void* d_out, int out_size, void* d_ws, size_t ws_size,
                              hipStream_t stream) {
    const float* h   = (const float*)d_in[0];
    const float* w   = (const float*)d_in[1];
    const int*   src = (const int*)d_in[2];
    const int*   dst = (const int*)d_in[3];
    const float* W   = (const float*)d_in[4];
    const float* b   = (const float*)d_in[5];
    float* out = (float*)d_out;

    int N = in_sizes[0] / D;
    int E = in_sizes[1];
    int numWords = (E + 31) / 32;

    auto align256 = [](size_t x) { return (x + 255) & ~(size_t)255; };
    size_t cursorB = align256((size_t)N * 4);
    size_t ovB     = align256((size_t)numWords * 4);
    size_t pairsB  = align256((size_t)N * CAP * 4);
    size_t gB      = align256((size_t)N * D * 2);
    size_t need = cursorB + ovB + pairsB + gB;

    if (ws_size >= need && N <= (1 << 17)) {
        char* p = (char*)d_ws;
        int*      cursor = (int*)p;       p += cursorB;
        unsigned* ovBits = (unsigned*)p;  p += ovB;
        unsigned* pairs  = (unsigned*)p;  p += pairsB;
        ushort*   g      = (ushort*)p;

        // cursor + ovBits are contiguous: one memset
        hipMemsetAsync(cursor, 0, cursorB + ovB, stream);

        // 8 shards x 512 slices = 4096 blocks (occupancy is the scatter's
        // limiter: 512->2048 blocks gave 112->86 us)
        scatter_shard_kernel<<<4096, 256, 0, stream>>>(src, dst, w, cursor,
                                                       ovBits, pairs, E, N);
        gemm_fused_kernel<<<(N + 63) / 64, 256, 0, stream>>>(h, W, b, out, g, N);
        final_agg_kernel<<<(N + 3) / 4, 256, 0, stream>>>(g, pairs, cursor, out, N);
        overflow_kernel<<<64, 256, 0, stream>>>(ovBits, src, dst, w, g, out, numWords);
    } else {
        float* agg = out;
        hipMemsetAsync(agg, 0, (size_t)N * D * 4, stream);
        edge_scatter_kernel<<<(E + 3) / 4, 256, 0, stream>>>(h, w, src, dst, agg, E);
        out_linear_kernel<<<2048, 256, 0, stream>>>(h, agg, W, b, out, N);
    }
}